// Round 1
// baseline (366.645 us; speedup 1.0000x reference)
//
#include <hip/hip_runtime.h>
#include <hip/hip_bf16.h>

// Output: 8 groups, each [16384, 256] fp32, concatenated flat (group-major).
// out[g][r][c] = in[r][g*512 + (c/32)*64 + (c%32)]
// All strides are powers of two -> shifts/masks only.
//
// Per output float4 (4 consecutive floats, c%4==0 within one 32-wide slice):
//   tid      : float4 index into out, [0, 8*16384*64)
//   g   = tid >> 20          (16384 rows * 64 float4/row = 2^20 per group)
//   rem = tid & 0xFFFFF
//   r   = rem >> 6
//   c4  = rem & 63           (float4 column within group output row)
//   j   = c4 >> 3            (which 32-wide slice)
//   w4  = c4 & 7             (float4 within the slice)
//   in col (float4 units) = g*128 + j*16 + w4   (512/4, 64/4)
//   in row stride (float4 units) = 4096/4 = 1024

__global__ __launch_bounds__(256) void
FuseSliceCatSameInputModule_v2_5720896438285_kernel(const float4* __restrict__ in,
                                                    float4* __restrict__ out) {
    const int tid = blockIdx.x * blockDim.x + threadIdx.x;  // float4 index
    const int g   = tid >> 20;
    const int rem = tid & ((1 << 20) - 1);
    const int r   = rem >> 6;
    const int c4  = rem & 63;
    const int j   = c4 >> 3;
    const int w4  = c4 & 7;
    const int incol4 = (g << 7) + (j << 4) + w4;
    out[tid] = in[r * 1024 + incol4];
}

extern "C" void kernel_launch(void* const* d_in, const int* in_sizes, int n_in,
                              void* d_out, int out_size, void* d_ws, size_t ws_size,
                              hipStream_t stream) {
    const float4* in  = (const float4*)d_in[0];
    float4*       out = (float4*)d_out;
    // total output float4s: 8 * 16384 * 64 = 8,388,608
    const int n4 = 8 * 16384 * 64;
    const int block = 256;
    const int grid = n4 / block;  // 32768
    FuseSliceCatSameInputModule_v2_5720896438285_kernel<<<grid, block, 0, stream>>>(in, out);
}

// Round 2
// 356.275 us; speedup vs baseline: 1.0291x; 1.0291x over previous
//
#include <hip/hip_runtime.h>
#include <hip/hip_bf16.h>

// Output: 8 groups, each [16384, 256] fp32, concatenated flat (group-major).
// out[g][r][c] = in[r][g*512 + (c/32)*64 + (c%32)]
//
// R2 change vs R1: block-index swizzle g = blockIdx & 7 (was g-major grid).
// Rationale: with g-major ordering, each phase of the grid holds address bits
// 11-13 of the input constant (g*2048 within a 16 KiB row), engaging only a
// subset of HBM channels and traversing the input 8x sparsely. Interleaving g
// across consecutive blocks makes concurrent accesses cover all channel bits
// and consumes each input row region exactly once (8 neighbor blocks read the
// 8 column bands of the same rows).
//
// Block = 256 threads = 4 waves. Each block: group g, rows 4*rblk..4*rblk+3.
// Wave (64 lanes) covers one output row's 64 float4s -> writes 1 KiB
// contiguous; reads eight 128-B aligned chunks within a 2 KiB span.

__global__ __launch_bounds__(256) void
FuseSliceCatSameInputModule_v2_5720896438285_kernel(const float4* __restrict__ in,
                                                    float4* __restrict__ out) {
    const int b    = blockIdx.x;
    const int g    = b & 7;        // group varies fastest across blocks
    const int rblk = b >> 3;       // 0..4095 (4 rows per block)
    const int t    = threadIdx.x;  // 0..255
    const int rloc = t >> 6;       // row within block, 0..3
    const int c4   = t & 63;       // float4 column within group output row
    const int r    = (rblk << 2) + rloc;
    const int j    = c4 >> 3;      // which 32-wide slice
    const int w4   = c4 & 7;       // float4 within the slice
    const int incol4  = (g << 7) + (j << 4) + w4;  // input col in float4 units
    const int out_idx = (g << 20) + (r << 6) + c4; // group-major output
    out[out_idx] = in[r * 1024 + incol4];
}

extern "C" void kernel_launch(void* const* d_in, const int* in_sizes, int n_in,
                              void* d_out, int out_size, void* d_ws, size_t ws_size,
                              hipStream_t stream) {
    const float4* in  = (const float4*)d_in[0];
    float4*       out = (float4*)d_out;
    const int block = 256;
    const int grid  = 8 * 4096;  // 8 groups x (16384 rows / 4 rows per block)
    FuseSliceCatSameInputModule_v2_5720896438285_kernel<<<grid, block, 0, stream>>>(in, out);
}